// Round 8
// baseline (204.357 us; speedup 1.0000x reference)
//
#include <hip/hip_runtime.h>
#include <math.h>

// ---------------------------------------------------------------------------
// Dual CTC loss forward, linear-probability fp64 recursion, beta-normalized
// B/L split form (validated R6), forward/backward split (validated R15).
// R16: R15 with the spill removed.
//  R15 post-mortem: WRITE_SIZE=3.1MB (vs 2KB in R9) = register-spill scratch
//  traffic. 16-row bufA+bufB (128 VGPR) + state surviving into the merge
//  exceeds the compiler's sticky 112-VGPR budget (R13: launch_bounds can't
//  move it) -> ~6 dwords/step spilled, reload latency on the serial critical
//  path (+170 cyc/step) ate the halved-depth win (290 cyc/step).
//  Fix (R14's lesson applied to the split): 8-row groups (buffers = 64 VGPR
//  at P=4), 7-row tails, renorm cadence 8. Fit the envelope; don't fight RA.
//  error task:   B=32, T=2000, C=4,  S=50   (inline f from raw logits)
//  phoneme task: B=32, T=2000, C=64, S=200  (Gph r-values, float4/lane)
// Falls back to the R2 proven path if ws too small.
// ---------------------------------------------------------------------------

static constexpr float  LOG2E = 1.4426950408889634f;
static constexpr double LN2D  = 0.6931471805599453;
static constexpr int GROWS = 2032;  // padded rows per chain

#define DPP_WAVE_SHL1   0x130
#define DPP_WAVE_SHR1   0x138
#define DPP_ROW_SHR(n)  (0x110 | (n))
#define DPP_ROW_BCAST15 0x142
#define DPP_ROW_BCAST31 0x143

__device__ __forceinline__ float fexp2(float x) {
  return __builtin_amdgcn_exp2f(x);
}
__device__ __forceinline__ float flog2(float x) {
  return __builtin_amdgcn_logf(x);
}

// prev-lane value (lane i gets lane i-1; lane 0 gets 0.0) — pure VALU
__device__ __forceinline__ double dpp_shr1_f64(double x) {
  int lo = __double2loint(x), hi = __double2hiint(x);
  lo = __builtin_amdgcn_update_dpp(0, lo, DPP_WAVE_SHR1, 0xf, 0xf, true);
  hi = __builtin_amdgcn_update_dpp(0, hi, DPP_WAVE_SHR1, 0xf, 0xf, true);
  return __hiloint2double(hi, lo);
}

// next-lane value (lane i gets lane i+1; lane 63 gets 0.0)
__device__ __forceinline__ double dpp_shl1_f64(double x) {
  int lo = __double2loint(x), hi = __double2hiint(x);
  lo = __builtin_amdgcn_update_dpp(0, lo, DPP_WAVE_SHL1, 0xf, 0xf, true);
  hi = __builtin_amdgcn_update_dpp(0, hi, DPP_WAVE_SHL1, 0xf, 0xf, true);
  return __hiloint2double(hi, lo);
}

__device__ __forceinline__ int imax2(int a, int b) { return a > b ? a : b; }

__device__ __forceinline__ int wave_imax(int v) {
  v = imax2(v, __builtin_amdgcn_update_dpp(0, v, DPP_ROW_SHR(1), 0xf, 0xf, true));
  v = imax2(v, __builtin_amdgcn_update_dpp(0, v, DPP_ROW_SHR(2), 0xf, 0xf, true));
  v = imax2(v, __builtin_amdgcn_update_dpp(0, v, DPP_ROW_SHR(4), 0xf, 0xf, true));
  v = imax2(v, __builtin_amdgcn_update_dpp(0, v, DPP_ROW_SHR(8), 0xf, 0xf, true));
  v = imax2(v, __builtin_amdgcn_update_dpp(0, v, DPP_ROW_BCAST15, 0xf, 0xf, true));
  v = imax2(v, __builtin_amdgcn_update_dpp(0, v, DPP_ROW_BCAST31, 0xf, 0xf, true));
  return __builtin_amdgcn_readlane(v, 63);
}

// ========================= fast path =======================================

// Slim gather (R13-proven): phoneme r-values + both Lpb arrays + out zero.
__global__ __launch_bounds__(256) void gather_ph_kernel(
    const float* __restrict__ ph_logits, const float* __restrict__ err_logits,
    const int* __restrict__ ph_tgt,
    float* __restrict__ Gph, float* __restrict__ Lpb_ph,
    float* __restrict__ Lpb_er, float* __restrict__ out) {
  const int bx = blockIdx.x, b = blockIdx.y;
  const int tid = threadIdx.x;
  const int lane = tid & 63, wv = tid >> 6;

  if (bx == 0 && b == 0 && tid == 0) *out = 0.f;  // chain kernel comes after

  // ---- error Lpb (wave 0, lanes 0..31) ----
  if (wv == 0 && lane < 32) {
    const int t = bx * 32 + lane;
    if (t < 2000) {
      const float4 v = *(const float4*)(err_logits + ((size_t)b * 2000 + t) * 4);
      const float z0 = v.x * LOG2E;
      const float s = fexp2(z0) + fexp2(v.y * LOG2E) + fexp2(v.z * LOG2E) +
                      fexp2(v.w * LOG2E);
      Lpb_er[(size_t)b * GROWS + t] = z0 - flog2(s);
    }
  }

  // ---- phoneme: 8 rows per wave ----
  const int* tb = ph_tgt + b * 200;
  int idx[4];
  float msk[4];
#pragma unroll
  for (int k = 0; k < 4; ++k) {
    const int si = lane * 4 + k;
    const int cls = (si < 200) ? tb[si] : 0;
    idx[k] = cls << 2;
    msk[k] = (si < 200) ? 1.0f : 0.0f;
  }
  const int t0 = (bx * 4 + wv) * 8;
  float z[8], e[8], s[8];
#pragma unroll
  for (int u = 0; u < 8; ++u) {
    const int t = t0 + u;
    const int tc = (t < 2000) ? t : 1999;
    z[u] = ph_logits[((size_t)b * 2000 + tc) * 64 + lane] * LOG2E;
    e[u] = fexp2(z[u]);
    s[u] = e[u];
  }
#pragma unroll
  for (int off = 32; off >= 1; off >>= 1) {
#pragma unroll
    for (int u = 0; u < 8; ++u) s[u] += __shfl_xor(s[u], off, 64);
  }
#pragma unroll
  for (int u = 0; u < 8; ++u) {
    const int t = t0 + u;
    if (t < 2000) {
      const float e0 = __int_as_float(
          __builtin_amdgcn_readlane(__float_as_int(e[u]), 0));
      const float inv0 = 1.0f / e0;
      float o[4];
#pragma unroll
      for (int k = 0; k < 4; ++k) {
        const float v = __int_as_float(
            __builtin_amdgcn_ds_bpermute(idx[k], __float_as_int(e[u])));
        o[k] = msk[k] * v * inv0;
      }
      *(float4*)(Gph + ((size_t)b * GROWS + t) * 256 + lane * 4) =
          make_float4(o[0], o[1], o[2], o[3]);
      if (lane == 0)  // lane 0's z is z0*log2e
        Lpb_ph[(size_t)b * GROWS + t] = z[u] - flog2(s[u]);
    }
  }
}

template <int P> struct RowP { float v[P]; };

// renorm band to ~2^(tgt-1023). fwd: tgt=1523 (2^500); bwd: tgt=1023 (2^0).
template <int P>
__device__ __forceinline__ void bl_renorm(double (&B)[P], double (&L)[P],
                                          int& K, int tgt) {
  double mm = B[0];
#pragma unroll
  for (int k = 0; k < P; ++k) mm = fmax(fmax(mm, B[k]), L[k]);
  const int ex = (__double2hiint(mm) >> 20) & 0x7ff;
  const int emax = wave_imax(ex);
  if (emax > 0) {
    int d = tgt - emax;
    if (d > 1023) d = 1023;
    if (d < -1022) d = -1022;
    const double sc = __hiloint2double((d + 1023) << 20, 0);
#pragma unroll
    for (int k = 0; k < P; ++k) { B[k] *= sc; L[k] *= sc; }
    K += d;
  }
}

// forward step (R9-proven): alpha over rows ascending.
template <int P>
__device__ __forceinline__ void bl_step(double (&B)[P], double (&L)[P],
                                        const double (&skipm)[P],
                                        const RowP<P>& f) {
  const double Lm1 = dpp_shr1_f64(L[P - 1]);
  double nB[P], nL[P];
#pragma unroll
  for (int k = 0; k < P; ++k) {
    const double Lp = (k >= 1) ? L[k - 1] : Lm1;
    nB[k] = B[k] + Lp;
    nL[k] = (double)f.v[k] * fma(skipm[k], Lp, B[k] + L[k]);
  }
#pragma unroll
  for (int k = 0; k < P; ++k) { B[k] = nB[k]; L[k] = nL[k]; }
}

// backward step (R15-proven): beta over rows descending. f = row t+1.
template <int P>
__device__ __forceinline__ void bl_step_bwd(double (&B)[P], double (&L)[P],
                                            const double (&sknext)[P],
                                            const RowP<P>& f) {
  double w[P];
#pragma unroll
  for (int k = 0; k < P; ++k) w[k] = (double)f.v[k] * L[k];
  const double wN = dpp_shl1_f64(w[0]);   // lane i gets lane i+1's w[0]
  const double BN = dpp_shl1_f64(B[0]);   // lane i+1's B[0]
  double nB[P], nL[P];
#pragma unroll
  for (int k = 0; k < P; ++k) {
    const double wp1 = (k < P - 1) ? w[k + 1] : wN;
    const double Bp1 = (k < P - 1) ? B[k + 1] : BN;
    nB[k] = B[k] + w[k];
    nL[k] = fma(sknext[k], wp1, w[k] + Bp1);
  }
#pragma unroll
  for (int k = 0; k < P; ++k) { B[k] = nB[k]; L[k] = nL[k]; }
}

// spb = sum_{t<len} Lpb[t], lane-parallel, x8 ILP
__device__ __forceinline__ float spb_sum(const float* __restrict__ Lpb,
                                         int len, int lane) {
  float spb = 0.f;
  for (int t0 = lane; t0 < len; t0 += 512) {
#pragma unroll
    for (int u = 0; u < 8; ++u) {
      const int t = t0 + u * 64;
      const int tc = (t < len) ? t : 0;        // always-valid address
      const float v = Lpb[tc];
      spb += (t < len) ? v : 0.0f;             // cndmask, no branch
    }
  }
#pragma unroll
  for (int off = 32; off >= 1; off >>= 1) spb += __shfl_xor(spb, off, 64);
  return spb;
}

// Interleaved double-buffer loop, forward: consumes rows 1..nsteps.
// 8-row groups: bufA+bufB = 64 VGPR at P=4 -> fits the 112-VGPR envelope.
template <int P, typename LdF, typename UseF>
__device__ __forceinline__ void run_fwd(int nsteps, LdF ldrow, UseF use,
                                        double (&B)[P], double (&L)[P],
                                        const double (&sk)[P], int& K) {
  using Buf = decltype(ldrow(1));
  const int ng = nsteps / 8;
  Buf bufA[8], bufB[8];
  if (ng >= 1) {
#pragma unroll
    for (int u = 0; u < 8; ++u) bufA[u] = ldrow(1 + u);
  }
  if (ng >= 2) {
#pragma unroll
    for (int u = 0; u < 8; ++u) bufB[u] = ldrow(9 + u);
  }
  int g = 0;
  for (; g + 2 <= ng; g += 2) {
    bl_renorm<P>(B, L, K, 1523);
    {
      const int gn = (g + 2 < ng) ? (g + 2) : 0;  // clamp re-reads rows 1..8
#pragma unroll
      for (int u = 0; u < 8; ++u) {
        bl_step<P>(B, L, sk, use(bufA[u]));
        bufA[u] = ldrow(1 + gn * 8 + u);
      }
    }
    bl_renorm<P>(B, L, K, 1523);
    {
      const int gn = (g + 3 < ng) ? (g + 3) : 0;
#pragma unroll
      for (int u = 0; u < 8; ++u) {
        bl_step<P>(B, L, sk, use(bufB[u]));
        bufB[u] = ldrow(1 + gn * 8 + u);
      }
    }
  }
  if (g < ng) {
    bl_renorm<P>(B, L, K, 1523);
#pragma unroll
    for (int u = 0; u < 8; ++u) bl_step<P>(B, L, sk, use(bufA[u]));
    ++g;
  }
  {  // tail rows 1+ng*8 .. nsteps (<=7)
    const int tstart = 1 + ng * 8;
    Buf bufT[7];
#pragma unroll
    for (int u = 0; u < 7; ++u) {
      int t = tstart + u;
      if (t > nsteps) t = (nsteps > 0) ? nsteps : 1;  // valid address
      bufT[u] = ldrow(t);
    }
#pragma unroll
    for (int u = 0; u < 7; ++u) {
      if (tstart + u <= nsteps) {
        if (u == 0) bl_renorm<P>(B, L, K, 1523);
        bl_step<P>(B, L, sk, use(bufT[u]));
      }
    }
  }
}

// backward: M steps consuming rows len-1, len-2, ..., len-M (descending).
template <int P, typename LdF, typename UseF>
__device__ __forceinline__ void run_bwd(int len, int M, LdF ldrow, UseF use,
                                        double (&B)[P], double (&L)[P],
                                        const double (&sk)[P], int& K) {
  using Buf = decltype(ldrow(1));
  const int ng = M / 8;
  Buf bufA[8], bufB[8];
  if (ng >= 1) {
#pragma unroll
    for (int u = 0; u < 8; ++u) bufA[u] = ldrow(len - 1 - u);
  }
  if (ng >= 2) {
#pragma unroll
    for (int u = 0; u < 8; ++u) bufB[u] = ldrow(len - 9 - u);
  }
  int g = 0;
  for (; g + 2 <= ng; g += 2) {
    bl_renorm<P>(B, L, K, 1023);
    {
      const int jb = (g + 2 < ng) ? (g + 2) * 8 : 0;  // clamp re-reads top
#pragma unroll
      for (int u = 0; u < 8; ++u) {
        bl_step_bwd<P>(B, L, sk, use(bufA[u]));
        bufA[u] = ldrow(len - 1 - jb - u);
      }
    }
    bl_renorm<P>(B, L, K, 1023);
    {
      const int jb = (g + 3 < ng) ? (g + 3) * 8 : 0;
#pragma unroll
      for (int u = 0; u < 8; ++u) {
        bl_step_bwd<P>(B, L, sk, use(bufB[u]));
        bufB[u] = ldrow(len - 1 - jb - u);
      }
    }
  }
  if (g < ng) {
    bl_renorm<P>(B, L, K, 1023);
#pragma unroll
    for (int u = 0; u < 8; ++u) bl_step_bwd<P>(B, L, sk, use(bufA[u]));
    ++g;
  }
  {  // tail j = ng*8 .. M-1 (<=7), row = len-1-j
    const int jstart = ng * 8;
    Buf bufT[7];
#pragma unroll
    for (int u = 0; u < 7; ++u) {
      int j = jstart + u;
      if (j > M - 1) j = (M > 0) ? (M - 1) : 0;  // valid address
      bufT[u] = ldrow(len - 1 - j);
    }
#pragma unroll
    for (int u = 0; u < 7; ++u) {
      if (jstart + u < M) {
        if (u == 0) bl_renorm<P>(B, L, K, 1023);
        bl_step_bwd<P>(B, L, sk, use(bufT[u]));
      }
    }
  }
}

// ---- phoneme chain: P=4, Gph float4/lane rows, fwd wave0 / bwd wave1. ----
__device__ __forceinline__ void chain_ph_fb(
    const float* __restrict__ Glab, const float* __restrict__ Lpb,
    const int* __restrict__ tb, int len, int tl, float* __restrict__ out,
    double* sBb, double* sLb, int* sKb) {
  constexpr int P = 4, S = 200, LSTRIDE = 256;
  const int tid = threadIdx.x;
  const int wave = tid >> 6, lane = tid & 63;
  const int t_mid = len >> 1;           // fwd steps = t_mid (rows 1..t_mid)
  const int M = (len - 1) - t_mid;      // bwd steps (rows len-1 .. t_mid+1)
  const float* gp = Glab + lane * P;

  auto ldrow = [&](int t) {
    RowP<P> r;
    const float4 a = *(const float4*)(gp + (size_t)t * LSTRIDE);
    r.v[0] = a.x; r.v[1] = a.y; r.v[2] = a.z; r.v[3] = a.w;
    return r;
  };
  auto use_id = [](const RowP<P>& r) { return r; };

  float spb = 0.f;
  double B[P], L[P];
  int Kf = 0;

  if (wave == 0) {
    // ---------------- forward ----------------
    spb = spb_sum(Lpb, len, lane);
    double skipm[P];
#pragma unroll
    for (int k = 0; k < P; ++k) {
      const int s = lane * P + k;
      skipm[k] = (s >= 1 && s < S && tb[s] != tb[s - 1]) ? 1.0 : 0.0;
    }
#pragma unroll
    for (int k = 0; k < P; ++k) { B[k] = 0.0; L[k] = 0.0; }
    {
      const float r0 = Glab[0];  // lane0 slot0 = r_{tgt[0]}(0)
      if (lane == 0) { B[0] = 1.0; L[0] = (double)r0; }
    }
    run_fwd<P>(t_mid, ldrow, use_id, B, L, skipm, Kf);
  } else {
    // ---------------- backward ----------------
    double sknext[P];
#pragma unroll
    for (int k = 0; k < P; ++k) {
      const int s = lane * P + k;
      sknext[k] = (s + 1 < S && tb[s + 1] != tb[s]) ? 1.0 : 0.0;
    }
    double Bb[P], Lb[P];
#pragma unroll
    for (int k = 0; k < P; ++k) {
      const int s = lane * P + k;
      Bb[k] = (s == tl) ? 1.0 : 0.0;       // state 2*tl (final blank)
      Lb[k] = (s == tl - 1) ? 1.0 : 0.0;   // state 2*tl-1 (last label)
    }
    int Kb = 0;
    run_bwd<P>(len, M, ldrow, use_id, Bb, Lb, sknext, Kb);
#pragma unroll
    for (int k = 0; k < P; ++k) {
      sBb[lane * P + k] = Bb[k];
      sLb[lane * P + k] = Lb[k];
    }
    if (lane == 0) *sKb = Kb;
  }
  __syncthreads();
  if (wave == 0) {
    double dot = 0.0;
#pragma unroll
    for (int k = 0; k < P; ++k)
      dot += B[k] * sBb[lane * P + k] + L[k] * sLb[lane * P + k];
#pragma unroll
    for (int off = 32; off >= 1; off >>= 1) dot += __shfl_xor(dot, off, 64);
    if (lane == 0) {
      const int K2 = Kf + *sKb;
      float loss = (float)((double)K2 * LN2D - log(dot) - (double)spb * LN2D);
      if (!(loss < 1e29f)) loss = 0.f;  // zero_infinity
      atomicAdd(out, loss / ((float)tl * 32.0f));
    }
  }
}

// ---- error chain: P=1, RAW logits rows (broadcast float4), inline f. ----
__device__ __forceinline__ void chain_er_fb(
    const float* __restrict__ zb, const float* __restrict__ Lpb,
    const int* __restrict__ tb, int len, int tl, float* __restrict__ out,
    double* sBb, double* sLb, int* sKb) {
  constexpr int P = 1, S = 50;
  const int tid = threadIdx.x;
  const int wave = tid >> 6, lane = tid & 63;
  const int t_mid = len >> 1;
  const int M = (len - 1) - t_mid;
  const float4* zr = (const float4*)zb;

  const int c1 = tb[(lane < S) ? lane : (S - 1)];
  const float fmask = (lane < S) ? 1.0f : 0.0f;

  auto ldrow = [&](int t) { return zr[t]; };
  auto mkf = [&](const float4& q) {
    RowP<P> f;
    const float zc = (c1 == 1) ? q.y : (c1 == 2) ? q.z : q.w;
    f.v[0] = fmask * fexp2((zc - q.x) * LOG2E);
    return f;
  };

  float spb = 0.f;
  double B[P], L[P];
  int Kf = 0;

  if (wave == 0) {
    spb = spb_sum(Lpb, len, lane);
    double skipm[P];
    skipm[0] =
        (lane >= 1 && lane < S && tb[lane] != tb[lane - 1]) ? 1.0 : 0.0;
    B[0] = 0.0; L[0] = 0.0;
    {
      const float4 q0 = zr[0];
      const int c0 = tb[0];
      const float zc = (c0 == 1) ? q0.y : (c0 == 2) ? q0.z : q0.w;
      if (lane == 0) {
        B[0] = 1.0;
        L[0] = (double)fexp2((zc - q0.x) * LOG2E);
      }
    }
    run_fwd<P>(t_mid, ldrow, mkf, B, L, skipm, Kf);
  } else {
    double sknext[P];
    sknext[0] = (lane + 1 < S && tb[lane + 1] != tb[lane]) ? 1.0 : 0.0;
    double Bb[P], Lb[P];
    Bb[0] = (lane == tl) ? 1.0 : 0.0;
    Lb[0] = (lane == tl - 1) ? 1.0 : 0.0;
    int Kb = 0;
    run_bwd<P>(len, M, ldrow, mkf, Bb, Lb, sknext, Kb);
    sBb[lane] = Bb[0];
    sLb[lane] = Lb[0];
    if (lane == 0) *sKb = Kb;
  }
  __syncthreads();
  if (wave == 0) {
    double dot = B[0] * sBb[lane] + L[0] * sLb[lane];
#pragma unroll
    for (int off = 32; off >= 1; off >>= 1) dot += __shfl_xor(dot, off, 64);
    if (lane == 0) {
      const int K2 = Kf + *sKb;
      float loss = (float)((double)K2 * LN2D - log(dot) - (double)spb * LN2D);
      if (!(loss < 1e29f)) loss = 0.f;
      atomicAdd(out, loss / ((float)tl * 32.0f));
    }
  }
}

__global__ __launch_bounds__(128) void ctc_chains_fbsplit_kernel(
    const float* __restrict__ Gph, const float* __restrict__ err_logits,
    const int* __restrict__ ph_tgt, const int* __restrict__ err_tgt,
    const int* __restrict__ err_il, const int* __restrict__ ph_il,
    const int* __restrict__ err_tl, const int* __restrict__ ph_tl,
    const float* __restrict__ Lpb_ph, const float* __restrict__ Lpb_er,
    float* __restrict__ out) {
  __shared__ double sBb[256], sLb[256];
  __shared__ int sKb;
  const int blk = blockIdx.x;
  if (blk < 32) {
    int len = err_il[blk]; if (len > 2000) len = 2000;
    chain_er_fb(err_logits + (size_t)blk * 2000 * 4,
                Lpb_er + (size_t)blk * GROWS, err_tgt + blk * 50, len,
                err_tl[blk], out, sBb, sLb, &sKb);
  } else {
    const int b = blk - 32;
    int len = ph_il[b]; if (len > 2000) len = 2000;
    chain_ph_fb(Gph + (size_t)b * GROWS * 256,
                Lpb_ph + (size_t)b * GROWS, ph_tgt + b * 200, len,
                ph_tl[b], out, sBb, sLb, &sKb);
  }
}

// ========================= fallback path (R2, proven) ======================

__global__ __launch_bounds__(256) void softmax4_kernel(
    const float* __restrict__ x, float* __restrict__ p, int nrows) {
  int r = blockIdx.x * blockDim.x + threadIdx.x;
  if (r >= nrows) return;
  float4 v = *reinterpret_cast<const float4*>(x + (size_t)r * 4);
  float z0 = v.x * LOG2E, z1 = v.y * LOG2E, z2 = v.z * LOG2E, z3 = v.w * LOG2E;
  float m = fmaxf(fmaxf(z0, z1), fmaxf(z2, z3));
  float e0 = fexp2(z0 - m), e1 = fexp2(z1 - m);
  float e2 = fexp2(z2 - m), e3 = fexp2(z3 - m);
  float inv = 1.0f / (e0 + e1 + e2 + e3);
  float4 o;
  o.x = e0 * inv; o.y = e1 * inv; o.z = e2 * inv; o.w = e3 * inv;
  *reinterpret_cast<float4*>(p + (size_t)r * 4) = o;
}

__global__ __launch_bounds__(256) void softmax64_kernel(
    const float* __restrict__ x, float* __restrict__ p, int nrows) {
  int row = blockIdx.x * 4 + (threadIdx.x >> 6);
  int lane = threadIdx.x & 63;
  if (row >= nrows) return;
  float z = x[(size_t)row * 64 + lane] * LOG2E;
  float m = z;
#pragma unroll
  for (int off = 32; off >= 1; off >>= 1) m = fmaxf(m, __shfl_xor(m, off, 64));
  float e = fexp2(z - m);
  float s = e;
#pragma unroll
  for (int off = 32; off >= 1; off >>= 1) s += __shfl_xor(s, off, 64);
  p[(size_t)row * 64 + lane] = e * (1.0f / s);
}

template <int C, int S, int R>
__device__ __forceinline__ void ctc_chain_lin_fb(
    const float* __restrict__ p_b, const int* __restrict__ tgt_b,
    int len, int tl, float* __restrict__ out, double* sa) {
  constexpr int L = 2 * S + 1;
  const int lane = threadIdx.x;
  int idx[R];
  double skipm[R];
#pragma unroll
  for (int j = 0; j < R; ++j) {
    const int l = lane * R + j;
    int cls = 0;
    bool sk = false;
    if (l & 1) {
      const int s = (l - 1) >> 1;
      const int sc = (s < S) ? s : (S - 1);
      cls = tgt_b[sc];
      if (s >= 1 && s < S) sk = (cls != tgt_b[s - 1]);
    }
    idx[j] = cls * 4;
    skipm[j] = sk ? 1.0 : 0.0;
  }
  double alpha[R];
#pragma unroll
  for (int j = 0; j < R; ++j) {
    const int l = lane * R + j;
    alpha[j] = (l <= 1) ? (double)p_b[idx[j] >> 2] : 0.0;
  }
  int K = 0;
  const int cl = lane & (C - 1);
  float rv = p_b[(size_t)((1 < len - 1) ? 1 : (len - 1)) * C + cl];
  float pf[R];
#pragma unroll
  for (int j = 0; j < R; ++j)
    pf[j] = __int_as_float(__builtin_amdgcn_ds_bpermute(idx[j], __float_as_int(rv)));
  rv = p_b[(size_t)((2 < len - 1) ? 2 : (len - 1)) * C + cl];
  for (int t = 1; t < len; ++t) {
    if ((t & 31) == 0) {
      double m = alpha[0];
#pragma unroll
      for (int j = 1; j < R; ++j) m = fmax(m, alpha[j]);
#pragma unroll
      for (int off = 1; off < 64; off <<= 1) m = fmax(m, __shfl_xor(m, off, 64));
      const long long bits = __double_as_longlong(m);
      const int e = (int)((bits >> 52) & 0x7FF);
      if (e > 0) {
        const double sc = __longlong_as_double((long long)(2046 - e) << 52);
#pragma unroll
        for (int j = 0; j < R; ++j) alpha[j] *= sc;
        K += 1023 - e;
      }
    }
    const int tn = (t + 2 < len) ? (t + 2) : (len - 1);
    const float rvn = p_b[(size_t)tn * C + cl];
    float pfn[R];
#pragma unroll
    for (int j = 0; j < R; ++j)
      pfn[j] = __int_as_float(__builtin_amdgcn_ds_bpermute(idx[j], __float_as_int(rv)));
    double am1 = __shfl_up(alpha[R - 1], 1, 64);
    double am2 = __shfl_up(alpha[R - 2], 1, 64);
    if (lane == 0) { am1 = 0.0; am2 = 0.0; }
    double na[R];
#pragma unroll
    for (int j = 0; j < R; ++j) {
      const double a0 = alpha[j];
      const double a1 = (j >= 1) ? alpha[j - 1] : am1;
      const double a2 = (j >= 2) ? alpha[j - 2] : ((j == 1) ? am1 : am2);
      double s = a0 + a1;
      s = fma(skipm[j], a2, s);
      na[j] = (double)pf[j] * s;
    }
#pragma unroll
    for (int j = 0; j < R; ++j) alpha[j] = na[j];
#pragma unroll
    for (int j = 0; j < R; ++j) pf[j] = pfn[j];
    rv = rvn;
  }
#pragma unroll
  for (int j = 0; j < R; ++j) {
    const int l = lane * R + j;
    if (l < L) sa[l] = alpha[j];
  }
  __syncthreads();
  if (lane == 0) {
    const double a = sa[2 * tl - 1] + sa[2 * tl];
    float loss = (float)((double)K * LN2D - log(a));
    if (!(loss < 1e29f)) loss = 0.0f;
    atomicAdd(out, loss / ((float)tl * 32.0f));
  }
}

__global__ __launch_bounds__(64) void ctc_chains_fb_kernel(
    const float* __restrict__ p_err, const float* __restrict__ p_ph,
    const int* __restrict__ err_tgt, const int* __restrict__ ph_tgt,
    const int* __restrict__ err_il, const int* __restrict__ ph_il,
    const int* __restrict__ err_tl, const int* __restrict__ ph_tl,
    float* __restrict__ out) {
  __shared__ double sa[512];
  const int T = 2000;
  const int blk = blockIdx.x;
  if (blk < 32) {
    const int b = blk;
    int len = err_il[b]; if (len > T) len = T;
    ctc_chain_lin_fb<4, 50, 2>(p_err + (size_t)b * T * 4, err_tgt + b * 50, len,
                               err_tl[b], out, sa);
  } else {
    const int b = blk - 32;
    int len = ph_il[b]; if (len > T) len = T;
    ctc_chain_lin_fb<64, 200, 7>(p_ph + (size_t)b * T * 64, ph_tgt + b * 200,
                                 len, ph_tl[b], out, sa);
  }
}

// ========================= launch ==========================================

extern "C" void kernel_launch(void* const* d_in, const int* in_sizes, int n_in,
                              void* d_out, int out_size, void* d_ws,
                              size_t ws_size, hipStream_t stream) {
  const float* err_logits = (const float*)d_in[0];
  const float* ph_logits  = (const float*)d_in[1];
  const int* err_tgt = (const int*)d_in[2];
  const int* ph_tgt  = (const int*)d_in[3];
  const int* err_il  = (const int*)d_in[4];
  const int* ph_il   = (const int*)d_in[5];
  const int* err_tl  = (const int*)d_in[6];
  const int* ph_tl   = (const int*)d_in[7];
  float* out = (float*)d_out;

  const size_t gph = (size_t)32 * GROWS * 256;  // 66.6 MB
  const size_t lpb = (size_t)32 * GROWS;        // per task
  const size_t need = (gph + 2 * lpb) * sizeof(float);

  if (ws_size >= need) {
    float* Gph = (float*)d_ws;
    float* Lpb_ph = Gph + gph;
    float* Lpb_er = Lpb_ph + lpb;
    // gather zeroes *out (chain kernel is stream-ordered after it)
    gather_ph_kernel<<<dim3(63, 32), 256, 0, stream>>>(
        ph_logits, err_logits, ph_tgt, Gph, Lpb_ph, Lpb_er, out);
    ctc_chains_fbsplit_kernel<<<64, 128, 0, stream>>>(
        Gph, err_logits, ph_tgt, err_tgt, err_il, ph_il, err_tl, ph_tl,
        Lpb_ph, Lpb_er, out);
  } else {
    (void)hipMemsetAsync(d_out, 0, sizeof(float), stream);
    const int B = 32, T = 2000;
    const int rows = B * T;
    float* p_err = (float*)d_ws;
    float* p_ph  = p_err + (size_t)rows * 4;
    softmax4_kernel<<<(rows + 255) / 256, 256, 0, stream>>>(err_logits, p_err, rows);
    softmax64_kernel<<<(rows + 3) / 4, 256, 0, stream>>>(ph_logits, p_ph, rows);
    ctc_chains_fb_kernel<<<64, 64, 0, stream>>>(p_err, p_ph, err_tgt, ph_tgt,
                                                err_il, ph_il, err_tl, ph_tl, out);
  }
}

// Round 9
// 202.239 us; speedup vs baseline: 1.0105x; 1.0105x over previous
//
#include <hip/hip_runtime.h>
#include <math.h>

// ---------------------------------------------------------------------------
// Dual CTC loss forward, linear-probability fp64 recursion, beta-normalized
// B/L split form (validated R6), forward/backward split (validated R15).
// R17: fwd and bwd in SEPARATE BLOCKS (R9-shaped), merge in a 3rd dispatch.
//  R15/R16 post-mortem: the merged fwd/bwd kernel spills regardless of
//  buffer size (R15: 16-row, VGPR112 + 3.1MB spill; R16: 8-row, VGPR64 +
//  1.6MB spill) — the divergent two-role block with state surviving
//  __syncthreads is allocator-hostile. R9's clean single-wave kernel shape
//  (one role, no cross-wave state) got VGPR112 / 2KB writes / 101us.
//  So: 128 blocks x 64 thr; block = (dir, chain); dir0 = R9 forward for
//  t_mid steps, dir1 = R15 backward for len-1-t_mid steps; each dumps B/L
//  (<=2KB) + K (+spb) to ws; 64-wave merge kernel dots and reduces.
//  error task:   B=32, T=2000, C=4,  S=50   (inline f from raw logits)
//  phoneme task: B=32, T=2000, C=64, S=200  (Gph r-values, float4/lane)
// Falls back to the R2 proven path if ws too small.
// ---------------------------------------------------------------------------

static constexpr float  LOG2E = 1.4426950408889634f;
static constexpr double LN2D  = 0.6931471805599453;
static constexpr int GROWS = 2032;  // padded rows per chain

#define DPP_WAVE_SHL1   0x130
#define DPP_WAVE_SHR1   0x138
#define DPP_ROW_SHR(n)  (0x110 | (n))
#define DPP_ROW_BCAST15 0x142
#define DPP_ROW_BCAST31 0x143

__device__ __forceinline__ float fexp2(float x) {
  return __builtin_amdgcn_exp2f(x);
}
__device__ __forceinline__ float flog2(float x) {
  return __builtin_amdgcn_logf(x);
}

// prev-lane value (lane i gets lane i-1; lane 0 gets 0.0) — pure VALU
__device__ __forceinline__ double dpp_shr1_f64(double x) {
  int lo = __double2loint(x), hi = __double2hiint(x);
  lo = __builtin_amdgcn_update_dpp(0, lo, DPP_WAVE_SHR1, 0xf, 0xf, true);
  hi = __builtin_amdgcn_update_dpp(0, hi, DPP_WAVE_SHR1, 0xf, 0xf, true);
  return __hiloint2double(hi, lo);
}

// next-lane value (lane i gets lane i+1; lane 63 gets 0.0)
__device__ __forceinline__ double dpp_shl1_f64(double x) {
  int lo = __double2loint(x), hi = __double2hiint(x);
  lo = __builtin_amdgcn_update_dpp(0, lo, DPP_WAVE_SHL1, 0xf, 0xf, true);
  hi = __builtin_amdgcn_update_dpp(0, hi, DPP_WAVE_SHL1, 0xf, 0xf, true);
  return __hiloint2double(hi, lo);
}

__device__ __forceinline__ int imax2(int a, int b) { return a > b ? a : b; }

__device__ __forceinline__ int wave_imax(int v) {
  v = imax2(v, __builtin_amdgcn_update_dpp(0, v, DPP_ROW_SHR(1), 0xf, 0xf, true));
  v = imax2(v, __builtin_amdgcn_update_dpp(0, v, DPP_ROW_SHR(2), 0xf, 0xf, true));
  v = imax2(v, __builtin_amdgcn_update_dpp(0, v, DPP_ROW_SHR(4), 0xf, 0xf, true));
  v = imax2(v, __builtin_amdgcn_update_dpp(0, v, DPP_ROW_SHR(8), 0xf, 0xf, true));
  v = imax2(v, __builtin_amdgcn_update_dpp(0, v, DPP_ROW_BCAST15, 0xf, 0xf, true));
  v = imax2(v, __builtin_amdgcn_update_dpp(0, v, DPP_ROW_BCAST31, 0xf, 0xf, true));
  return __builtin_amdgcn_readlane(v, 63);
}

// ========================= fast path =======================================

// Slim gather (R13-proven): phoneme r-values + both Lpb arrays + out zero.
__global__ __launch_bounds__(256) void gather_ph_kernel(
    const float* __restrict__ ph_logits, const float* __restrict__ err_logits,
    const int* __restrict__ ph_tgt,
    float* __restrict__ Gph, float* __restrict__ Lpb_ph,
    float* __restrict__ Lpb_er, float* __restrict__ out) {
  const int bx = blockIdx.x, b = blockIdx.y;
  const int tid = threadIdx.x;
  const int lane = tid & 63, wv = tid >> 6;

  if (bx == 0 && b == 0 && tid == 0) *out = 0.f;  // chain kernels come after

  // ---- error Lpb (wave 0, lanes 0..31) ----
  if (wv == 0 && lane < 32) {
    const int t = bx * 32 + lane;
    if (t < 2000) {
      const float4 v = *(const float4*)(err_logits + ((size_t)b * 2000 + t) * 4);
      const float z0 = v.x * LOG2E;
      const float s = fexp2(z0) + fexp2(v.y * LOG2E) + fexp2(v.z * LOG2E) +
                      fexp2(v.w * LOG2E);
      Lpb_er[(size_t)b * GROWS + t] = z0 - flog2(s);
    }
  }

  // ---- phoneme: 8 rows per wave ----
  const int* tb = ph_tgt + b * 200;
  int idx[4];
  float msk[4];
#pragma unroll
  for (int k = 0; k < 4; ++k) {
    const int si = lane * 4 + k;
    const int cls = (si < 200) ? tb[si] : 0;
    idx[k] = cls << 2;
    msk[k] = (si < 200) ? 1.0f : 0.0f;
  }
  const int t0 = (bx * 4 + wv) * 8;
  float z[8], e[8], s[8];
#pragma unroll
  for (int u = 0; u < 8; ++u) {
    const int t = t0 + u;
    const int tc = (t < 2000) ? t : 1999;
    z[u] = ph_logits[((size_t)b * 2000 + tc) * 64 + lane] * LOG2E;
    e[u] = fexp2(z[u]);
    s[u] = e[u];
  }
#pragma unroll
  for (int off = 32; off >= 1; off >>= 1) {
#pragma unroll
    for (int u = 0; u < 8; ++u) s[u] += __shfl_xor(s[u], off, 64);
  }
#pragma unroll
  for (int u = 0; u < 8; ++u) {
    const int t = t0 + u;
    if (t < 2000) {
      const float e0 = __int_as_float(
          __builtin_amdgcn_readlane(__float_as_int(e[u]), 0));
      const float inv0 = 1.0f / e0;
      float o[4];
#pragma unroll
      for (int k = 0; k < 4; ++k) {
        const float v = __int_as_float(
            __builtin_amdgcn_ds_bpermute(idx[k], __float_as_int(e[u])));
        o[k] = msk[k] * v * inv0;
      }
      *(float4*)(Gph + ((size_t)b * GROWS + t) * 256 + lane * 4) =
          make_float4(o[0], o[1], o[2], o[3]);
      if (lane == 0)  // lane 0's z is z0*log2e
        Lpb_ph[(size_t)b * GROWS + t] = z[u] - flog2(s[u]);
    }
  }
}

template <int P> struct RowP { float v[P]; };

// renorm band to ~2^(tgt-1023). fwd: tgt=1523 (2^500); bwd: tgt=1023 (2^0).
template <int P>
__device__ __forceinline__ void bl_renorm(double (&B)[P], double (&L)[P],
                                          int& K, int tgt) {
  double mm = B[0];
#pragma unroll
  for (int k = 0; k < P; ++k) mm = fmax(fmax(mm, B[k]), L[k]);
  const int ex = (__double2hiint(mm) >> 20) & 0x7ff;
  const int emax = wave_imax(ex);
  if (emax > 0) {
    int d = tgt - emax;
    if (d > 1023) d = 1023;
    if (d < -1022) d = -1022;
    const double sc = __hiloint2double((d + 1023) << 20, 0);
#pragma unroll
    for (int k = 0; k < P; ++k) { B[k] *= sc; L[k] *= sc; }
    K += d;
  }
}

// forward step (R9-proven): alpha over rows ascending.
template <int P>
__device__ __forceinline__ void bl_step(double (&B)[P], double (&L)[P],
                                        const double (&skipm)[P],
                                        const RowP<P>& f) {
  const double Lm1 = dpp_shr1_f64(L[P - 1]);
  double nB[P], nL[P];
#pragma unroll
  for (int k = 0; k < P; ++k) {
    const double Lp = (k >= 1) ? L[k - 1] : Lm1;
    nB[k] = B[k] + Lp;
    nL[k] = (double)f.v[k] * fma(skipm[k], Lp, B[k] + L[k]);
  }
#pragma unroll
  for (int k = 0; k < P; ++k) { B[k] = nB[k]; L[k] = nL[k]; }
}

// backward step (R15-proven): beta over rows descending. f = row t+1.
template <int P>
__device__ __forceinline__ void bl_step_bwd(double (&B)[P], double (&L)[P],
                                            const double (&sknext)[P],
                                            const RowP<P>& f) {
  double w[P];
#pragma unroll
  for (int k = 0; k < P; ++k) w[k] = (double)f.v[k] * L[k];
  const double wN = dpp_shl1_f64(w[0]);   // lane i gets lane i+1's w[0]
  const double BN = dpp_shl1_f64(B[0]);   // lane i+1's B[0]
  double nB[P], nL[P];
#pragma unroll
  for (int k = 0; k < P; ++k) {
    const double wp1 = (k < P - 1) ? w[k + 1] : wN;
    const double Bp1 = (k < P - 1) ? B[k + 1] : BN;
    nB[k] = B[k] + w[k];
    nL[k] = fma(sknext[k], wp1, w[k] + Bp1);
  }
#pragma unroll
  for (int k = 0; k < P; ++k) { B[k] = nB[k]; L[k] = nL[k]; }
}

// spb = sum_{t<len} Lpb[t], lane-parallel, x8 ILP
__device__ __forceinline__ float spb_sum(const float* __restrict__ Lpb,
                                         int len, int lane) {
  float spb = 0.f;
  for (int t0 = lane; t0 < len; t0 += 512) {
#pragma unroll
    for (int u = 0; u < 8; ++u) {
      const int t = t0 + u * 64;
      const int tc = (t < len) ? t : 0;        // always-valid address
      const float v = Lpb[tc];
      spb += (t < len) ? v : 0.0f;             // cndmask, no branch
    }
  }
#pragma unroll
  for (int off = 32; off >= 1; off >>= 1) spb += __shfl_xor(spb, off, 64);
  return spb;
}

// R9-proven interleaved double-buffer loop (16-row groups), forward:
// consumes rows 1..nsteps.
template <int P, typename LdF, typename UseF>
__device__ __forceinline__ void run_fwd(int nsteps, LdF ldrow, UseF use,
                                        double (&B)[P], double (&L)[P],
                                        const double (&sk)[P], int& K) {
  using Buf = decltype(ldrow(1));
  const int ng = nsteps / 16;
  Buf bufA[16], bufB[16];
  if (ng >= 1) {
#pragma unroll
    for (int u = 0; u < 16; ++u) bufA[u] = ldrow(1 + u);
  }
  if (ng >= 2) {
#pragma unroll
    for (int u = 0; u < 16; ++u) bufB[u] = ldrow(17 + u);
  }
  int g = 0;
  for (; g + 2 <= ng; g += 2) {
    bl_renorm<P>(B, L, K, 1523);
    {
      const int gn = (g + 2 < ng) ? (g + 2) : 0;  // clamp re-reads rows 1..16
#pragma unroll
      for (int u = 0; u < 16; ++u) {
        bl_step<P>(B, L, sk, use(bufA[u]));
        bufA[u] = ldrow(1 + gn * 16 + u);
      }
    }
    bl_renorm<P>(B, L, K, 1523);
    {
      const int gn = (g + 3 < ng) ? (g + 3) : 0;
#pragma unroll
      for (int u = 0; u < 16; ++u) {
        bl_step<P>(B, L, sk, use(bufB[u]));
        bufB[u] = ldrow(1 + gn * 16 + u);
      }
    }
  }
  if (g < ng) {
    bl_renorm<P>(B, L, K, 1523);
#pragma unroll
    for (int u = 0; u < 16; ++u) bl_step<P>(B, L, sk, use(bufA[u]));
    ++g;
  }
  {  // tail rows 1+ng*16 .. nsteps (<=15)
    const int tstart = 1 + ng * 16;
    Buf bufT[15];
#pragma unroll
    for (int u = 0; u < 15; ++u) {
      int t = tstart + u;
      if (t > nsteps) t = (nsteps > 0) ? nsteps : 1;  // valid address
      bufT[u] = ldrow(t);
    }
#pragma unroll
    for (int u = 0; u < 15; ++u) {
      if (tstart + u <= nsteps) {
        if (u == 0) bl_renorm<P>(B, L, K, 1523);
        bl_step<P>(B, L, sk, use(bufT[u]));
      }
    }
  }
}

// backward: M steps consuming rows len-1, len-2, ..., len-M (descending).
template <int P, typename LdF, typename UseF>
__device__ __forceinline__ void run_bwd(int len, int M, LdF ldrow, UseF use,
                                        double (&B)[P], double (&L)[P],
                                        const double (&sk)[P], int& K) {
  using Buf = decltype(ldrow(1));
  const int ng = M / 16;
  Buf bufA[16], bufB[16];
  if (ng >= 1) {
#pragma unroll
    for (int u = 0; u < 16; ++u) bufA[u] = ldrow(len - 1 - u);
  }
  if (ng >= 2) {
#pragma unroll
    for (int u = 0; u < 16; ++u) bufB[u] = ldrow(len - 17 - u);
  }
  int g = 0;
  for (; g + 2 <= ng; g += 2) {
    bl_renorm<P>(B, L, K, 1023);
    {
      const int jb = (g + 2 < ng) ? (g + 2) * 16 : 0;  // clamp re-reads top
#pragma unroll
      for (int u = 0; u < 16; ++u) {
        bl_step_bwd<P>(B, L, sk, use(bufA[u]));
        bufA[u] = ldrow(len - 1 - jb - u);
      }
    }
    bl_renorm<P>(B, L, K, 1023);
    {
      const int jb = (g + 3 < ng) ? (g + 3) * 16 : 0;
#pragma unroll
      for (int u = 0; u < 16; ++u) {
        bl_step_bwd<P>(B, L, sk, use(bufB[u]));
        bufB[u] = ldrow(len - 1 - jb - u);
      }
    }
  }
  if (g < ng) {
    bl_renorm<P>(B, L, K, 1023);
#pragma unroll
    for (int u = 0; u < 16; ++u) bl_step_bwd<P>(B, L, sk, use(bufA[u]));
    ++g;
  }
  {  // tail j = ng*16 .. M-1 (<=15), row = len-1-j
    const int jstart = ng * 16;
    Buf bufT[15];
#pragma unroll
    for (int u = 0; u < 15; ++u) {
      int j = jstart + u;
      if (j > M - 1) j = (M > 0) ? (M - 1) : 0;  // valid address
      bufT[u] = ldrow(len - 1 - j);
    }
#pragma unroll
    for (int u = 0; u < 15; ++u) {
      if (jstart + u < M) {
        if (u == 0) bl_renorm<P>(B, L, K, 1023);
        bl_step_bwd<P>(B, L, sk, use(bufT[u]));
      }
    }
  }
}

// ---------------------------------------------------------------------------
// Half kernel: 128 blocks x 64 thr. blk = dir*64 + c.
//  dir 0 = forward  (rows 1 .. t_mid),   dumps Bf/Lf + Kf + spb.
//  dir 1 = backward (rows len-1 .. t_mid+1), dumps Bb/Lb + Kb.
// Chain c: c<32 error (P=1, inline f from raw logits), c>=32 phoneme (P=4).
// State layout: st + (c*4 + {0,1,2,3})*256 = Bf, Lf, Bb, Lb (doubles).
// Ks[c] = Kf, Ks[64+c] = Kb. spbA[c] by fwd lane0.
// ---------------------------------------------------------------------------
__global__ __launch_bounds__(64) void ctc_half_kernel(
    const float* __restrict__ Gph, const float* __restrict__ err_logits,
    const int* __restrict__ ph_tgt, const int* __restrict__ err_tgt,
    const int* __restrict__ err_il, const int* __restrict__ ph_il,
    const int* __restrict__ err_tl, const int* __restrict__ ph_tl,
    const float* __restrict__ Lpb_ph, const float* __restrict__ Lpb_er,
    double* __restrict__ st, int* __restrict__ Ks,
    float* __restrict__ spbA) {
  const int blk = blockIdx.x;
  const int dir = blk >> 6;        // 0 fwd, 1 bwd
  const int c = blk & 63;
  const int lane = threadIdx.x;

  double* stB = st + ((size_t)c * 4 + (dir ? 2 : 0)) * 256;
  double* stL = st + ((size_t)c * 4 + (dir ? 3 : 1)) * 256;

  if (c < 32) {
    // ================= error chain, P=1 =================
    constexpr int P = 1, S = 50;
    const int* tb = err_tgt + c * 50;
    int len = err_il[c]; if (len > 2000) len = 2000;
    const int tl = err_tl[c];
    const int t_mid = len >> 1;
    const int M = (len - 1) - t_mid;
    const float4* zr = (const float4*)(err_logits + (size_t)c * 2000 * 4);

    const int c1 = tb[(lane < S) ? lane : (S - 1)];
    const float fmask = (lane < S) ? 1.0f : 0.0f;
    auto ldrow = [&](int t) { return zr[t]; };
    auto mkf = [&](const float4& q) {
      RowP<P> f;
      const float zc = (c1 == 1) ? q.y : (c1 == 2) ? q.z : q.w;
      f.v[0] = fmask * fexp2((zc - q.x) * LOG2E);
      return f;
    };

    double B[P], L[P];
    int K = 0;
    if (dir == 0) {
      const float spb = spb_sum(Lpb_er + (size_t)c * GROWS, len, lane);
      double skipm[P];
      skipm[0] =
          (lane >= 1 && lane < S && tb[lane] != tb[lane - 1]) ? 1.0 : 0.0;
      B[0] = 0.0; L[0] = 0.0;
      {
        const float4 q0 = zr[0];
        const int c0 = tb[0];
        const float zc = (c0 == 1) ? q0.y : (c0 == 2) ? q0.z : q0.w;
        if (lane == 0) {
          B[0] = 1.0;
          L[0] = (double)fexp2((zc - q0.x) * LOG2E);
        }
      }
      run_fwd<P>(t_mid, ldrow, mkf, B, L, skipm, K);
      if (lane == 0) spbA[c] = spb;
    } else {
      double sknext[P];
      sknext[0] = (lane + 1 < S && tb[lane + 1] != tb[lane]) ? 1.0 : 0.0;
      B[0] = (lane == tl) ? 1.0 : 0.0;       // state 2*tl (final blank)
      L[0] = (lane == tl - 1) ? 1.0 : 0.0;   // state 2*tl-1 (last label)
      run_bwd<P>(len, M, ldrow, mkf, B, L, sknext, K);
    }
    stB[lane] = B[0];
    stL[lane] = L[0];
    if (lane == 0) Ks[dir * 64 + c] = K;
  } else {
    // ================= phoneme chain, P=4 =================
    constexpr int P = 4, S = 200, LSTRIDE = 256;
    const int b = c - 32;
    const int* tb = ph_tgt + b * 200;
    int len = ph_il[b]; if (len > 2000) len = 2000;
    const int tl = ph_tl[b];
    const int t_mid = len >> 1;
    const int M = (len - 1) - t_mid;
    const float* Glab = Gph + (size_t)b * GROWS * 256;
    const float* gp = Glab + lane * P;

    auto ldrow = [&](int t) {
      RowP<P> r;
      const float4 a = *(const float4*)(gp + (size_t)t * LSTRIDE);
      r.v[0] = a.x; r.v[1] = a.y; r.v[2] = a.z; r.v[3] = a.w;
      return r;
    };
    auto use_id = [](const RowP<P>& r) { return r; };

    double B[P], L[P];
    int K = 0;
    if (dir == 0) {
      const float spb = spb_sum(Lpb_ph + (size_t)b * GROWS, len, lane);
      double skipm[P];
#pragma unroll
      for (int k = 0; k < P; ++k) {
        const int s = lane * P + k;
        skipm[k] = (s >= 1 && s < S && tb[s] != tb[s - 1]) ? 1.0 : 0.0;
      }
#pragma unroll
      for (int k = 0; k < P; ++k) { B[k] = 0.0; L[k] = 0.0; }
      {
        const float r0 = Glab[0];  // lane0 slot0 = r_{tgt[0]}(0)
        if (lane == 0) { B[0] = 1.0; L[0] = (double)r0; }
      }
      run_fwd<P>(t_mid, ldrow, use_id, B, L, skipm, K);
      if (lane == 0) spbA[c] = spb;
    } else {
      double sknext[P];
#pragma unroll
      for (int k = 0; k < P; ++k) {
        const int s = lane * P + k;
        sknext[k] = (s + 1 < S && tb[s + 1] != tb[s]) ? 1.0 : 0.0;
      }
#pragma unroll
      for (int k = 0; k < P; ++k) {
        const int s = lane * P + k;
        B[k] = (s == tl) ? 1.0 : 0.0;
        L[k] = (s == tl - 1) ? 1.0 : 0.0;
      }
      run_bwd<P>(len, M, ldrow, use_id, B, L, sknext, K);
    }
#pragma unroll
    for (int k = 0; k < P; ++k) {
      stB[lane * P + k] = B[k];
      stL[lane * P + k] = L[k];
    }
    if (lane == 0) Ks[dir * 64 + c] = K;
  }
}

// Merge: 64 waves. dot = sum_s Bf*Bb + Lf*Lb at t_mid; loss from K2/spb.
__global__ __launch_bounds__(64) void ctc_merge_kernel(
    const double* __restrict__ st, const int* __restrict__ Ks,
    const float* __restrict__ spbA, const int* __restrict__ err_tl,
    const int* __restrict__ ph_tl, float* __restrict__ out) {
  const int c = blockIdx.x;
  const int lane = threadIdx.x;
  const double* Bf = st + ((size_t)c * 4 + 0) * 256;
  const double* Lf = st + ((size_t)c * 4 + 1) * 256;
  const double* Bb = st + ((size_t)c * 4 + 2) * 256;
  const double* Lb = st + ((size_t)c * 4 + 3) * 256;
  double dot;
  if (c < 32) {
    dot = Bf[lane] * Bb[lane] + Lf[lane] * Lb[lane];
  } else {
    dot = 0.0;
#pragma unroll
    for (int k = 0; k < 4; ++k) {
      const int i = lane * 4 + k;
      dot += Bf[i] * Bb[i] + Lf[i] * Lb[i];
    }
  }
#pragma unroll
  for (int off = 32; off >= 1; off >>= 1) dot += __shfl_xor(dot, off, 64);
  if (lane == 0) {
    const int K2 = Ks[c] + Ks[64 + c];
    const int tl = (c < 32) ? err_tl[c] : ph_tl[c - 32];
    float loss =
        (float)((double)K2 * LN2D - log(dot) - (double)spbA[c] * LN2D);
    if (!(loss < 1e29f)) loss = 0.f;  // zero_infinity
    atomicAdd(out, loss / ((float)tl * 32.0f));
  }
}

// ========================= fallback path (R2, proven) ======================

__global__ __launch_bounds__(256) void softmax4_kernel(
    const float* __restrict__ x, float* __restrict__ p, int nrows) {
  int r = blockIdx.x * blockDim.x + threadIdx.x;
  if (r >= nrows) return;
  float4 v = *reinterpret_cast<const float4*>(x + (size_t)r * 4);
  float z0 = v.x * LOG2E, z1 = v.y * LOG2E, z2 = v.z * LOG2E, z3 = v.w * LOG2E;
  float m = fmaxf(fmaxf(z0, z1), fmaxf(z2, z3));
  float e0 = fexp2(z0 - m), e1 = fexp2(z1 - m);
  float e2 = fexp2(z2 - m), e3 = fexp2(z3 - m);
  float inv = 1.0f / (e0 + e1 + e2 + e3);
  float4 o;
  o.x = e0 * inv; o.y = e1 * inv; o.z = e2 * inv; o.w = e3 * inv;
  *reinterpret_cast<float4*>(p + (size_t)r * 4) = o;
}

__global__ __launch_bounds__(256) void softmax64_kernel(
    const float* __restrict__ x, float* __restrict__ p, int nrows) {
  int row = blockIdx.x * 4 + (threadIdx.x >> 6);
  int lane = threadIdx.x & 63;
  if (row >= nrows) return;
  float z = x[(size_t)row * 64 + lane] * LOG2E;
  float m = z;
#pragma unroll
  for (int off = 32; off >= 1; off >>= 1) m = fmaxf(m, __shfl_xor(m, off, 64));
  float e = fexp2(z - m);
  float s = e;
#pragma unroll
  for (int off = 32; off >= 1; off >>= 1) s += __shfl_xor(s, off, 64);
  p[(size_t)row * 64 + lane] = e * (1.0f / s);
}

template <int C, int S, int R>
__device__ __forceinline__ void ctc_chain_lin_fb(
    const float* __restrict__ p_b, const int* __restrict__ tgt_b,
    int len, int tl, float* __restrict__ out, double* sa) {
  constexpr int L = 2 * S + 1;
  const int lane = threadIdx.x;
  int idx[R];
  double skipm[R];
#pragma unroll
  for (int j = 0; j < R; ++j) {
    const int l = lane * R + j;
    int cls = 0;
    bool sk = false;
    if (l & 1) {
      const int s = (l - 1) >> 1;
      const int sc = (s < S) ? s : (S - 1);
      cls = tgt_b[sc];
      if (s >= 1 && s < S) sk = (cls != tgt_b[s - 1]);
    }
    idx[j] = cls * 4;
    skipm[j] = sk ? 1.0 : 0.0;
  }
  double alpha[R];
#pragma unroll
  for (int j = 0; j < R; ++j) {
    const int l = lane * R + j;
    alpha[j] = (l <= 1) ? (double)p_b[idx[j] >> 2] : 0.0;
  }
  int K = 0;
  const int cl = lane & (C - 1);
  float rv = p_b[(size_t)((1 < len - 1) ? 1 : (len - 1)) * C + cl];
  float pf[R];
#pragma unroll
  for (int j = 0; j < R; ++j)
    pf[j] = __int_as_float(__builtin_amdgcn_ds_bpermute(idx[j], __float_as_int(rv)));
  rv = p_b[(size_t)((2 < len - 1) ? 2 : (len - 1)) * C + cl];
  for (int t = 1; t < len; ++t) {
    if ((t & 31) == 0) {
      double m = alpha[0];
#pragma unroll
      for (int j = 1; j < R; ++j) m = fmax(m, alpha[j]);
#pragma unroll
      for (int off = 1; off < 64; off <<= 1) m = fmax(m, __shfl_xor(m, off, 64));
      const long long bits = __double_as_longlong(m);
      const int e = (int)((bits >> 52) & 0x7FF);
      if (e > 0) {
        const double sc = __longlong_as_double((long long)(2046 - e) << 52);
#pragma unroll
        for (int j = 0; j < R; ++j) alpha[j] *= sc;
        K += 1023 - e;
      }
    }
    const int tn = (t + 2 < len) ? (t + 2) : (len - 1);
    const float rvn = p_b[(size_t)tn * C + cl];
    float pfn[R];
#pragma unroll
    for (int j = 0; j < R; ++j)
      pfn[j] = __int_as_float(__builtin_amdgcn_ds_bpermute(idx[j], __float_as_int(rv)));
    double am1 = __shfl_up(alpha[R - 1], 1, 64);
    double am2 = __shfl_up(alpha[R - 2], 1, 64);
    if (lane == 0) { am1 = 0.0; am2 = 0.0; }
    double na[R];
#pragma unroll
    for (int j = 0; j < R; ++j) {
      const double a0 = alpha[j];
      const double a1 = (j >= 1) ? alpha[j - 1] : am1;
      const double a2 = (j >= 2) ? alpha[j - 2] : ((j == 1) ? am1 : am2);
      double s = a0 + a1;
      s = fma(skipm[j], a2, s);
      na[j] = (double)pf[j] * s;
    }
#pragma unroll
    for (int j = 0; j < R; ++j) alpha[j] = na[j];
#pragma unroll
    for (int j = 0; j < R; ++j) pf[j] = pfn[j];
    rv = rvn;
  }
#pragma unroll
  for (int j = 0; j < R; ++j) {
    const int l = lane * R + j;
    if (l < L) sa[l] = alpha[j];
  }
  __syncthreads();
  if (lane == 0) {
    const double a = sa[2 * tl - 1] + sa[2 * tl];
    float loss = (float)((double)K * LN2D - log(a));
    if (!(loss < 1e29f)) loss = 0.0f;
    atomicAdd(out, loss / ((float)tl * 32.0f));
  }
}

__global__ __launch_bounds__(64) void ctc_chains_fb_kernel(
    const float* __restrict__ p_err, const float* __restrict__ p_ph,
    const int* __restrict__ err_tgt, const int* __restrict__ ph_tgt,
    const int* __restrict__ err_il, const int* __restrict__ ph_il,
    const int* __restrict__ err_tl, const int* __restrict__ ph_tl,
    float* __restrict__ out) {
  __shared__ double sa[512];
  const int T = 2000;
  const int blk = blockIdx.x;
  if (blk < 32) {
    const int b = blk;
    int len = err_il[b]; if (len > T) len = T;
    ctc_chain_lin_fb<4, 50, 2>(p_err + (size_t)b * T * 4, err_tgt + b * 50, len,
                               err_tl[b], out, sa);
  } else {
    const int b = blk - 32;
    int len = ph_il[b]; if (len > T) len = T;
    ctc_chain_lin_fb<64, 200, 7>(p_ph + (size_t)b * T * 64, ph_tgt + b * 200,
                                 len, ph_tl[b], out, sa);
  }
}

// ========================= launch ==========================================

extern "C" void kernel_launch(void* const* d_in, const int* in_sizes, int n_in,
                              void* d_out, int out_size, void* d_ws,
                              size_t ws_size, hipStream_t stream) {
  const float* err_logits = (const float*)d_in[0];
  const float* ph_logits  = (const float*)d_in[1];
  const int* err_tgt = (const int*)d_in[2];
  const int* ph_tgt  = (const int*)d_in[3];
  const int* err_il  = (const int*)d_in[4];
  const int* ph_il   = (const int*)d_in[5];
  const int* err_tl  = (const int*)d_in[6];
  const int* ph_tl   = (const int*)d_in[7];
  float* out = (float*)d_out;

  const size_t gph = (size_t)32 * GROWS * 256;  // floats, 66.6 MB
  const size_t lpb = (size_t)32 * GROWS;        // floats, per task
  const size_t nst = (size_t)64 * 4 * 256;      // doubles, 512 KB
  const size_t need =
      (gph + 2 * lpb) * sizeof(float) + nst * sizeof(double) + 256 * 4;

  if (ws_size >= need) {
    float* Gph = (float*)d_ws;
    float* Lpb_ph = Gph + gph;
    float* Lpb_er = Lpb_ph + lpb;
    double* st = (double*)(Lpb_er + lpb);  // 8B-aligned (offsets are 8B mult)
    int* Ks = (int*)(st + nst);            // 128 ints
    float* spbA = (float*)(Ks + 128);      // 64 floats
    // gather zeroes *out (chain kernels are stream-ordered after it)
    gather_ph_kernel<<<dim3(63, 32), 256, 0, stream>>>(
        ph_logits, err_logits, ph_tgt, Gph, Lpb_ph, Lpb_er, out);
    ctc_half_kernel<<<128, 64, 0, stream>>>(
        Gph, err_logits, ph_tgt, err_tgt, err_il, ph_il, err_tl, ph_tl,
        Lpb_ph, Lpb_er, st, Ks, spbA);
    ctc_merge_kernel<<<64, 64, 0, stream>>>(st, Ks, spbA, err_tl, ph_tl, out);
  } else {
    (void)hipMemsetAsync(d_out, 0, sizeof(float), stream);
    const int B = 32, T = 2000;
    const int rows = B * T;
    float* p_err = (float*)d_ws;
    float* p_ph  = p_err + (size_t)rows * 4;
    softmax4_kernel<<<(rows + 255) / 256, 256, 0, stream>>>(err_logits, p_err, rows);
    softmax64_kernel<<<(rows + 3) / 4, 256, 0, stream>>>(ph_logits, p_ph, rows);
    ctc_chains_fb_kernel<<<64, 64, 0, stream>>>(p_err, p_ph, err_tgt, ph_tgt,
                                                err_il, ph_il, err_tl, ph_tl, out);
  }
}